// Round 5
// baseline (671.097 us; speedup 1.0000x reference)
//
#include <hip/hip_runtime.h>

// ---------- lane/scalar helpers (all VALU-pipe, no DS ops) ----------

static __device__ __forceinline__ float rdlane(float v, int l) {
  return __uint_as_float(__builtin_amdgcn_readlane(__float_as_uint(v), (unsigned)l));
}
static __device__ __forceinline__ unsigned rdlane_u(float v, int l) {
  return __builtin_amdgcn_readlane(__float_as_uint(v), (unsigned)l);
}

template <int CTRL>
static __device__ __forceinline__ float qperm(float v) {
  // DPP quad_perm: pure VALU cross-lane within each 4-lane quad.
  return __uint_as_float(__builtin_amdgcn_update_dpp(
      0u, __float_as_uint(v), CTRL, 0xF, 0xF, true));
}

template <int N>
static __device__ __forceinline__ float rowror(float v) {
  // DPP row rotate (within each 16-lane row) — VALU pipe.
  return __uint_as_float(__builtin_amdgcn_update_dpp(
      0u, __float_as_uint(v), 0x120 | N, 0xF, 0xF, true));
}

// Cross-row exchange+add via gfx950 permlane swaps (VALU pipe, no DS).
// Explicit v_mov into an early-clobber register guarantees DISTINCT physical
// registers (tied "+v"/"+v" on one SSA value coalesces -> self-swap bug).
// s_nop 1 covers the VALU-write -> permlane-read wait-state hazard (the
// compiler cannot see inside this asm to insert it).
static __device__ __forceinline__ float xswapadd16(float v) {
  float a = v, b;
  asm("v_mov_b32 %0, %1\n\t"
      "s_nop 1\n\t"
      "v_permlane16_swap_b32 %1, %0"
      : "=&v"(b), "+v"(a));
  return a + b;  // rows {0,1} get r0+r1; rows {2,3} get r2+r3 (per 32-half)
}
static __device__ __forceinline__ float xswapadd32(float v) {
  float a = v, b;
  asm("v_mov_b32 %0, %1\n\t"
      "s_nop 1\n\t"
      "v_permlane32_swap_b32 %1, %0"
      : "=&v"(b), "+v"(a));
  return a + b;  // all lanes get lo32 + hi32
}

static __device__ __forceinline__ float exp2a(float x) {
  float r;
  asm("v_exp_f32 %0, %1" : "=v"(r) : "v"(x));
  return r;
}
static __device__ __forceinline__ float rcpa(float x) {
  return __builtin_amdgcn_rcpf(x);
}

// ---------- packed f32 (VGPR-pair) helpers: v_pk_* on gfx90a+ ----------
typedef float v2f __attribute__((ext_vector_type(2)));

// acc = sp * wp   (sp: uniform SGPR pair {lo,hi}; wp: per-lane VGPR pair)
static __device__ __forceinline__ v2f pk_mul_sv(unsigned long long sp, v2f wp) {
  v2f r;
  asm("v_pk_mul_f32 %0, %1, %2" : "=v"(r) : "s"(sp), "v"(wp));
  return r;
}
// acc += sp * wp
static __device__ __forceinline__ void pk_fma_sv(v2f& acc, unsigned long long sp, v2f wp) {
  asm("v_pk_fma_f32 %0, %1, %2, %0" : "+v"(acc) : "s"(sp), "v"(wp));
}
static __device__ __forceinline__ v2f pk_add(v2f a, v2f b) {
  v2f r;
  asm("v_pk_add_f32 %0, %1, %2" : "=v"(r) : "v"(a), "v"(b));
  return r;
}

#define QP_BC0 0x00  // broadcast quad lane 0 (i)
#define QP_BC1 0x55  // broadcast quad lane 1 (f)
#define QP_BC2 0xAA  // broadcast quad lane 2 (g)
#define QP_BC3 0xFF  // broadcast quad lane 3 (o)

// One wave64 per batch element. lane = 4*j + gt  (j: hidden unit 0..15,
// gt: gate 0..3 in torch order i,f,g,o; torch row = gt*16 + j).
//
// Scale folding (R3): sigmoid rows *= -log2e, g rows *= -2log2e; g-gate
// output pre-scaled by -2log2e so cs = -2log2e*c and tanh(c) =
// 2*rcp(1+exp2(cs)) - 1 with no input multiply.
//
// Pipeline (R4): body (ch,s) computes layer-2 for step g=ch*64+s and
// layer-1 for step g+1, both off h1(g) -> independent chains.
//
// NEW (R5): the 16-term Whh1.h matvec uses v_pk_fma_f32 on SGPR h-pairs:
// 16 readlane -> 8 uint64 SGPR pairs; 2 pk chains of 4; 12 instrs vs 20.
__global__ __launch_bounds__(64, 1) void vdd_lstm_kernel(
    const float* __restrict__ x,      // [B,T]
    const float* __restrict__ Wih1,   // [64]
    const float* __restrict__ Whh1,   // [64,16]
    const float* __restrict__ b1,     // [64]
    const float* __restrict__ Wih2,   // [4,16]
    const float* __restrict__ Whh2,   // [4]
    const float* __restrict__ b2,     // [4]
    const float* __restrict__ mask1,  // [B,16]
    const float* __restrict__ mask2,  // [B]
    float* __restrict__ out,          // [B,T]
    int T) {
  const int b = blockIdx.x;
  const int lane = threadIdx.x;  // block = 64 threads
  const int j = lane >> 2;
  const int gt = lane & 3;
  const int row = gt * 16 + j;

  const float LOG2E = 1.4426950408889634f;
  const bool isg = (gt == 2);
  const float sc = isg ? (-2.f * LOG2E) : (-LOG2E);
  const float aA = isg ? (-4.f * LOG2E) : 1.f;
  const float aC = isg ? (2.f * LOG2E) : 0.f;

  // Per-lane weights as 8 VGPR pairs {w[2m], w[2m+1]}, pre-scaled.
  v2f wp[8];
#pragma unroll
  for (int m = 0; m < 8; ++m) {
    wp[m].x = Whh1[row * 16 + 2 * m] * sc;
    wp[m].y = Whh1[row * 16 + 2 * m + 1] * sc;
  }
  const float wih1 = Wih1[row] * sc;
  const float bb1  = b1[row] * sc;
  const float w2l  = Wih2[gt * 16 + j] * mask1[b * 16 + j] * sc;
  const float whh2 = Whh2[gt] * sc;
  const float bb2  = b2[gt] * sc;
  const float m2   = mask2[b];

  const float* xb = x + (size_t)b * T;
  float* ob = out + (size_t)b * T;

  float h = 0.f, cs = 0.f;     // layer-1 state (all lanes)
  float cs2 = 0.f, h2b = 0.f;  // layer-2 state (all lanes)

  float xcur = xb[lane];       // x chunk [0,64)
  const int NCH = T >> 6;

  // ---- prologue: layer-1 for step 0 (h_prev = 0 -> no Whh1 term) ----
  {
    float sx = rdlane(xcur, 0);
    float pre = __fmaf_rn(wih1, sx, bb1);
    float a1 = __fmaf_rn(aA, rcpa(1.f + exp2a(pre)), aC);
    float i1 = qperm<QP_BC0>(a1);
    float g1 = qperm<QP_BC2>(a1);
    float o1 = qperm<QP_BC3>(a1);
    cs = i1 * g1;  // f*0 + i*g
    h = o1 * __fmaf_rn(2.f, rcpa(1.f + exp2a(cs)), -1.f);
  }

  for (int ch = 0; ch < NCH; ++ch) {
    int nb = (ch + 1) << 6;
    nb = (nb + 64 <= T) ? nb : 0;
    float xnext = xb[nb + lane];  // coalesced prefetch (dummy for last chunk)

    float och = 0.f;  // out chunk: lane L holds out[ch*64 + L]

#pragma unroll 8
    for (int s = 0; s < 64; ++s) {
      // ---- x for layer-1 of step g+1 (one ahead; crosses chunk at s=63)
      float xsrc = (s < 63) ? xcur : xnext;
      float sx = rdlane(xsrc, (s + 1) & 63);

      // ---- broadcast h=h1(g) into 8 SGPR pairs {h[2m], h[2m+1]}
      // (h[k] is quad-replicated: h[2m] at lane 8m, h[2m+1] at lane 8m+4;
      //  the u64 pack of two readlane results is register coalescing — SALU-free)
      unsigned long long sp[8];
#pragma unroll
      for (int m = 0; m < 8; ++m) {
        unsigned lo = rdlane_u(h, 8 * m);
        unsigned hi = rdlane_u(h, 8 * m + 4);
        sp[m] = (unsigned long long)lo | ((unsigned long long)hi << 32);
      }

      // layer-2 (step g): per-lane product for the in-wave reduction
      float v2 = h * w2l;

      // ---- layer-1 pre-activation via packed FMA: 2 chains of 4
      v2f accA = pk_mul_sv(sp[0], wp[0]);
      v2f accB = pk_mul_sv(sp[1], wp[1]);
      pk_fma_sv(accA, sp[2], wp[2]);
      pk_fma_sv(accB, sp[3], wp[3]);
      pk_fma_sv(accA, sp[4], wp[4]);
      pk_fma_sv(accB, sp[5], wp[5]);
      pk_fma_sv(accA, sp[6], wp[6]);
      pk_fma_sv(accB, sp[7], wp[7]);
      v2f accS = pk_add(accA, accB);
      float pre = __fmaf_rn(wih1, sx, bb1) + (accS.x + accS.y);

      // layer-2 reduction (independent of layer-1 chain)
      float r = v2 + rowror<4>(v2);
      r = r + rowror<8>(r);
      r = xswapadd16(r);
      r = xswapadd32(r);
      float pre2 = __fmaf_rn(whh2, h2b, bb2) + r;

      // layer-1 activation + state update -> h_new
      float a1 = __fmaf_rn(aA, rcpa(1.f + exp2a(pre)), aC);
      float i1 = qperm<QP_BC0>(a1);
      float f1 = qperm<QP_BC1>(a1);
      float g1 = qperm<QP_BC2>(a1);
      float o1 = qperm<QP_BC3>(a1);
      cs = __fmaf_rn(f1, cs, i1 * g1);
      float hn = o1 * __fmaf_rn(2.f, rcpa(1.f + exp2a(cs)), -1.f);

      // layer-2 activation + state update -> ov (wave-uniform)
      float a2 = __fmaf_rn(aA, rcpa(1.f + exp2a(pre2)), aC);
      float i2 = qperm<QP_BC0>(a2);
      float f2 = qperm<QP_BC1>(a2);
      float g2 = qperm<QP_BC2>(a2);
      float o2 = qperm<QP_BC3>(a2);
      cs2 = __fmaf_rn(f2, cs2, i2 * g2);
      h2b = o2 * __fmaf_rn(2.f, rcpa(1.f + exp2a(cs2)), -1.f);
      float ov = h2b * m2;

      och = (lane == s) ? ov : och;
      h = hn;
    }

    ob[(ch << 6) + lane] = och;  // coalesced store
    xcur = xnext;
  }
}

extern "C" void kernel_launch(void* const* d_in, const int* in_sizes, int n_in,
                              void* d_out, int out_size, void* d_ws, size_t ws_size,
                              hipStream_t stream) {
  const float* x     = (const float*)d_in[0];
  const float* Wih1  = (const float*)d_in[1];
  const float* Whh1  = (const float*)d_in[2];
  const float* b1    = (const float*)d_in[3];
  const float* Wih2  = (const float*)d_in[4];
  const float* Whh2  = (const float*)d_in[5];
  const float* b2    = (const float*)d_in[6];
  const float* mask1 = (const float*)d_in[7];
  const float* mask2 = (const float*)d_in[8];
  float* out = (float*)d_out;

  const int B = in_sizes[8];      // mask2 has B elements
  const int T = in_sizes[0] / B;  // x is [B,T,1]

  vdd_lstm_kernel<<<dim3(B), dim3(64), 0, stream>>>(
      x, Wih1, Whh1, b1, Wih2, Whh2, b2, mask1, mask2, out, T);
}

// Round 6
// 670.946 us; speedup vs baseline: 1.0002x; 1.0002x over previous
//
#include <hip/hip_runtime.h>

// ---------- lane/scalar helpers (all VALU-pipe, no DS/LDS ops) ----------

static __device__ __forceinline__ float rdlane(float v, int l) {
  return __uint_as_float(__builtin_amdgcn_readlane(__float_as_uint(v), (unsigned)l));
}

template <int CTRL>
static __device__ __forceinline__ float qperm(float v) {
  // DPP quad_perm: pure VALU cross-lane within each 4-lane quad.
  return __uint_as_float(__builtin_amdgcn_update_dpp(
      0u, __float_as_uint(v), CTRL, 0xF, 0xF, true));
}

static __device__ __forceinline__ float exp2a(float x) {
  float r;
  asm("v_exp_f32 %0, %1" : "=v"(r) : "v"(x));
  return r;
}
static __device__ __forceinline__ float rcpa(float x) {
  return __builtin_amdgcn_rcpf(x);
}

#define QP_BC0 0x00  // broadcast quad lane 0 (i)
#define QP_BC1 0x55  // broadcast quad lane 1 (f)
#define QP_BC2 0xAA  // broadcast quad lane 2 (g)
#define QP_BC3 0xFF  // broadcast quad lane 3 (o)

// One wave64 per batch element. lane = 4*j + gt  (j: hidden unit 0..15,
// gt: gate 0..3 in torch order i,f,g,o; torch row = gt*16 + j).
//
// Scale folding (R3): sigmoid rows *= -log2e, g rows *= -2log2e; g-gate
// output pre-scaled by -2log2e so cs = -2log2e*c and tanh(c) =
// 2*rcp(1+exp2(cs)) - 1 with no input multiply.
//
// Pipeline (R4): body (ch,s) computes layer-2 for step g=ch*64+s and
// layer-1 for step g+1, both consuming h1(g).
//
// NEW (R6): both layers share ONE readlane broadcast of h1(g). Layer-2's
// dot is a per-lane-redundant 16-term FMA tree with per-lane weights
// (Wih2[gt,k]*mask1[k]) — every lane of gate gt computes the same pre2.
// The DPP/permlane reduction (and its s_nops + inline-asm scheduling
// barriers, which sat on the L2 recurrence critical path) is GONE from
// the loop. Both recurrence chains are now short, balanced FMA trees.
__global__ __launch_bounds__(64, 1) void vdd_lstm_kernel(
    const float* __restrict__ x,      // [B,T]
    const float* __restrict__ Wih1,   // [64]
    const float* __restrict__ Whh1,   // [64,16]
    const float* __restrict__ b1,     // [64]
    const float* __restrict__ Wih2,   // [4,16]
    const float* __restrict__ Whh2,   // [4]
    const float* __restrict__ b2,     // [4]
    const float* __restrict__ mask1,  // [B,16]
    const float* __restrict__ mask2,  // [B]
    float* __restrict__ out,          // [B,T]
    int T) {
  const int b = blockIdx.x;
  const int lane = threadIdx.x;  // block = 64 threads
  const int j = lane >> 2;
  const int gt = lane & 3;
  const int row = gt * 16 + j;

  const float LOG2E = 1.4426950408889634f;
  const bool isg = (gt == 2);
  const float sc = isg ? (-2.f * LOG2E) : (-LOG2E);
  const float aA = isg ? (-4.f * LOG2E) : 1.f;
  const float aC = isg ? (2.f * LOG2E) : 0.f;

  // Layer-1 per-lane weights (row = this lane's gate row), pre-scaled.
  float w[16];
#pragma unroll
  for (int k = 0; k < 16; ++k) w[k] = Whh1[row * 16 + k] * sc;
  const float wih1 = Wih1[row] * sc;
  const float bb1  = b1[row] * sc;
  // Layer-2 per-lane weights over ALL 16 inputs (mask1 + scale folded).
  float w2m[16];
#pragma unroll
  for (int k = 0; k < 16; ++k) w2m[k] = Wih2[gt * 16 + k] * mask1[b * 16 + k] * sc;
  const float whh2 = Whh2[gt] * sc;
  const float bb2  = b2[gt] * sc;
  const float m2   = mask2[b];

  const float* xb = x + (size_t)b * T;
  float* ob = out + (size_t)b * T;

  float h = 0.f, cs = 0.f;     // layer-1 state (all lanes)
  float cs2 = 0.f, h2b = 0.f;  // layer-2 state (all lanes)

  float xcur = xb[lane];       // x chunk [0,64)
  const int NCH = T >> 6;

  // ---- prologue: layer-1 for step 0 (h_prev = 0 -> no Whh1 term) ----
  {
    float sx = rdlane(xcur, 0);
    float pre = __fmaf_rn(wih1, sx, bb1);
    float a1 = __fmaf_rn(aA, rcpa(1.f + exp2a(pre)), aC);
    float i1 = qperm<QP_BC0>(a1);
    float g1 = qperm<QP_BC2>(a1);
    float o1 = qperm<QP_BC3>(a1);
    cs = i1 * g1;  // f*0 + i*g
    h = o1 * __fmaf_rn(2.f, rcpa(1.f + exp2a(cs)), -1.f);
  }

  for (int ch = 0; ch < NCH; ++ch) {
    int nb = (ch + 1) << 6;
    nb = (nb + 64 <= T) ? nb : 0;
    float xnext = xb[nb + lane];  // coalesced prefetch (dummy for last chunk)

    float och = 0.f;  // out chunk: lane L holds out[ch*64 + L]

#pragma unroll 8
    for (int s = 0; s < 64; ++s) {
      // ---- x for layer-1 of step g+1 (one ahead; crosses chunk at s=63)
      float xsrc = (s < 63) ? xcur : xnext;
      float sx = rdlane(xsrc, (s + 1) & 63);

      // ---- ONE broadcast of h = h1(g) into SGPRs, shared by both layers
      float sh[16];
#pragma unroll
      for (int k = 0; k < 16; ++k) sh[k] = rdlane(h, 4 * k);

      // ---- layer-1 pre-activation (step g+1): Wih1*x + b1 + Whh1 . h
      float p0 = __fmaf_rn(wih1, sx, bb1);
      p0 = __fmaf_rn(w[0], sh[0], p0);
      float p1 = w[1] * sh[1];
      float p2 = w[2] * sh[2];
      float p3 = w[3] * sh[3];
#pragma unroll
      for (int k = 4; k < 16; k += 4) {
        p0 = __fmaf_rn(w[k + 0], sh[k + 0], p0);
        p1 = __fmaf_rn(w[k + 1], sh[k + 1], p1);
        p2 = __fmaf_rn(w[k + 2], sh[k + 2], p2);
        p3 = __fmaf_rn(w[k + 3], sh[k + 3], p3);
      }
      float pre = (p0 + p1) + (p2 + p3);

      // ---- layer-2 pre-activation (step g): per-lane redundant tree,
      //      same sh[] operands, per-lane (gate) weights. No cross-lane ops.
      float q0 = __fmaf_rn(whh2, h2b, bb2);
      q0 = __fmaf_rn(w2m[0], sh[0], q0);
      float q1 = w2m[1] * sh[1];
      float q2 = w2m[2] * sh[2];
      float q3 = w2m[3] * sh[3];
#pragma unroll
      for (int k = 4; k < 16; k += 4) {
        q0 = __fmaf_rn(w2m[k + 0], sh[k + 0], q0);
        q1 = __fmaf_rn(w2m[k + 1], sh[k + 1], q1);
        q2 = __fmaf_rn(w2m[k + 2], sh[k + 2], q2);
        q3 = __fmaf_rn(w2m[k + 3], sh[k + 3], q3);
      }
      float pre2 = (q0 + q1) + (q2 + q3);

      // ---- layer-1 activation + state update -> h_new
      float a1 = __fmaf_rn(aA, rcpa(1.f + exp2a(pre)), aC);
      float i1 = qperm<QP_BC0>(a1);
      float f1 = qperm<QP_BC1>(a1);
      float g1 = qperm<QP_BC2>(a1);
      float o1 = qperm<QP_BC3>(a1);
      cs = __fmaf_rn(f1, cs, i1 * g1);
      float hn = o1 * __fmaf_rn(2.f, rcpa(1.f + exp2a(cs)), -1.f);

      // ---- layer-2 activation + state update -> ov (wave-uniform)
      float a2 = __fmaf_rn(aA, rcpa(1.f + exp2a(pre2)), aC);
      float i2 = qperm<QP_BC0>(a2);
      float f2 = qperm<QP_BC1>(a2);
      float g2 = qperm<QP_BC2>(a2);
      float o2 = qperm<QP_BC3>(a2);
      cs2 = __fmaf_rn(f2, cs2, i2 * g2);
      h2b = o2 * __fmaf_rn(2.f, rcpa(1.f + exp2a(cs2)), -1.f);
      float ov = h2b * m2;

      och = (lane == s) ? ov : och;
      h = hn;
    }

    ob[(ch << 6) + lane] = och;  // coalesced store
    xcur = xnext;
  }
}

extern "C" void kernel_launch(void* const* d_in, const int* in_sizes, int n_in,
                              void* d_out, int out_size, void* d_ws, size_t ws_size,
                              hipStream_t stream) {
  const float* x     = (const float*)d_in[0];
  const float* Wih1  = (const float*)d_in[1];
  const float* Whh1  = (const float*)d_in[2];
  const float* b1    = (const float*)d_in[3];
  const float* Wih2  = (const float*)d_in[4];
  const float* Whh2  = (const float*)d_in[5];
  const float* b2    = (const float*)d_in[6];
  const float* mask1 = (const float*)d_in[7];
  const float* mask2 = (const float*)d_in[8];
  float* out = (float*)d_out;

  const int B = in_sizes[8];      // mask2 has B elements
  const int T = in_sizes[0] / B;  // x is [B,T,1]

  vdd_lstm_kernel<<<dim3(B), dim3(64), 0, stream>>>(
      x, Wih1, Whh1, b1, Wih2, Whh2, b2, mask1, mask2, out, T);
}

// Round 8
// 641.076 us; speedup vs baseline: 1.0468x; 1.0466x over previous
//
#include <hip/hip_runtime.h>

// ---------- types ----------
// NOTE: gfx builtins (cvt_pkrtz, fdot2) use __fp16 ext-vectors, NOT _Float16.
typedef __fp16 f16x2 __attribute__((ext_vector_type(2)));

// ---------- lane/scalar helpers ----------
static __device__ __forceinline__ float rdlane(float v, int l) {
  return __uint_as_float(__builtin_amdgcn_readlane(__float_as_uint(v), (unsigned)l));
}
static __device__ __forceinline__ unsigned rdlane_u(unsigned v, int l) {
  return __builtin_amdgcn_readlane(v, (unsigned)l);
}

template <int CTRL>
static __device__ __forceinline__ float qperm(float v) {
  // DPP quad_perm: explicit per-position select — direction-unambiguous.
  return __uint_as_float(__builtin_amdgcn_update_dpp(
      0u, __float_as_uint(v), CTRL, 0xF, 0xF, true));
}

static __device__ __forceinline__ float exp2a(float x) {
  float r;
  asm("v_exp_f32 %0, %1" : "=v"(r) : "v"(x));
  return r;
}
static __device__ __forceinline__ float rcpa(float x) {
  return __builtin_amdgcn_rcpf(x);
}

// f32 += f16x2 . f16x2  (v_dot2_f32_f16: f16 multiply, f32 accumulate)
static __device__ __forceinline__ float dot2f(f16x2 a, unsigned bu, float c) {
#if __has_builtin(__builtin_amdgcn_fdot2)
  return __builtin_amdgcn_fdot2(a, __builtin_bit_cast(f16x2, bu), c, false);
#else
  float r = c;
  f16x2 b = __builtin_bit_cast(f16x2, bu);
  asm("v_dot2_f32_f16 %0, %1, %2, %0" : "+v"(r) : "v"(a), "v"(b));
  return r;
#endif
}

#define QP_BC0 0x00  // broadcast quad lane 0 (i)
#define QP_BC1 0x55  // broadcast quad lane 1 (f)
#define QP_BC2 0xAA  // broadcast quad lane 2 (g)
#define QP_BC3 0xFF  // broadcast quad lane 3 (o)

// lane = 4*j + gt (j: hidden unit 0..15, gt: gate i,f,g,o; torch row gt*16+j).
//
// Scale folding (R3): sigmoid rows *= -log2e, g rows *= -2log2e; g-gate
// output pre-scaled so cs = -2log2e*c; tanh(c) = 2*rcp(1+exp2(cs)) - 1.
// Pipeline (R4): body step g computes L2(g) and L1(g+1), both off h1(g).
//
// R7/R8: both matvecs via v_dot2_f32_f16 on a SHARED f16 pair-broadcast:
//   hsw = ds_swizzle(h, xor-4)       (LDS pipe, direction-safe pairing)
//   tp  = cvt_pkrtz(h, hsw)          -> lane 8m holds {h[2m], h[2m+1]}
//   sp[m] = readlane(tp, 8m)         -> 8 SGPR f16-pairs (vs 16 readlanes)
//   L1: 8 dot2 (2 chains)            (vs 21-op f32 FMA tree)
//   L2: 8 dot2 (2 chains)            (vs rowror/permlane asm reduction)
// x window pre-shifted by +1 (clamped) -> per-step x = one readlane.
__global__ __launch_bounds__(64, 1) void vdd_lstm_kernel(
    const float* __restrict__ x,      // [B,T]
    const float* __restrict__ Wih1,   // [64]
    const float* __restrict__ Whh1,   // [64,16]
    const float* __restrict__ b1,     // [64]
    const float* __restrict__ Wih2,   // [4,16]
    const float* __restrict__ Whh2,   // [4]
    const float* __restrict__ b2,     // [4]
    const float* __restrict__ mask1,  // [B,16]
    const float* __restrict__ mask2,  // [B]
    float* __restrict__ out,          // [B,T]
    int T) {
  const int b = blockIdx.x;
  const int lane = threadIdx.x;  // 64 threads
  const int j = lane >> 2;
  const int gt = lane & 3;
  const int row = gt * 16 + j;

  const float LOG2E = 1.4426950408889634f;
  const bool isg = (gt == 2);
  const float sc = isg ? (-2.f * LOG2E) : (-LOG2E);
  const float aA = isg ? (-4.f * LOG2E) : 1.f;
  const float aC = isg ? (2.f * LOG2E) : 0.f;

  // L1 weights as 8 f16 pairs {w[2m], w[2m+1]} (pre-scaled; RTN casts).
  f16x2 wh1[8];
#pragma unroll
  for (int m = 0; m < 8; ++m) {
    wh1[m].x = (__fp16)(Whh1[row * 16 + 2 * m] * sc);
    wh1[m].y = (__fp16)(Whh1[row * 16 + 2 * m + 1] * sc);
  }
  // L2 weights (mask1 + scale folded) as 8 f16 pairs.
  f16x2 wh2[8];
#pragma unroll
  for (int m = 0; m < 8; ++m) {
    wh2[m].x = (__fp16)(Wih2[gt * 16 + 2 * m] * mask1[b * 16 + 2 * m] * sc);
    wh2[m].y = (__fp16)(Wih2[gt * 16 + 2 * m + 1] * mask1[b * 16 + 2 * m + 1] * sc);
  }
  const float wih1 = Wih1[row] * sc;
  const float bb1  = b1[row] * sc;
  const float whh2 = Whh2[gt] * sc;
  const float bb2  = b2[gt] * sc;
  const float m2   = mask2[b];

  const float* xb = x + (size_t)b * T;
  float* ob = out + (size_t)b * T;

  float h = 0.f, cs = 0.f;     // layer-1 state (all lanes)
  float cs2 = 0.f, h2b = 0.f;  // layer-2 state (all lanes)

  const int NCH = T >> 6;
  const int tmax = T - 1;

  // x window for chunk 0: x[1 + lane], clamped (coalesced).
  int idx0 = 1 + lane; idx0 = idx0 > tmax ? tmax : idx0;
  float xr = xb[idx0];

  // ---- prologue: layer-1 for step 0 (h_prev = 0) ----
  {
    float x0 = xb[0];  // uniform
    float pre = __fmaf_rn(wih1, x0, bb1);
    float a1 = __fmaf_rn(aA, rcpa(1.f + exp2a(pre)), aC);
    float i1 = qperm<QP_BC0>(a1);
    float g1 = qperm<QP_BC2>(a1);
    float o1 = qperm<QP_BC3>(a1);
    cs = i1 * g1;
    h = o1 * __fmaf_rn(2.f, rcpa(1.f + exp2a(cs)), -1.f);
  }

  for (int ch = 0; ch < NCH; ++ch) {
    // prefetch next chunk's shifted window (clamped; coalesced)
    int idxn = (ch + 1) * 64 + 1 + lane;
    idxn = idxn > tmax ? tmax : idxn;
    float xnext = xb[idxn];

    float och = 0.f;  // lane L accumulates out[ch*64 + L]

#pragma unroll 8
    for (int s = 0; s < 64; ++s) {
      // ---- shared f16 pair-broadcast of h = h1(g) ----
      unsigned hsw = (unsigned)__builtin_amdgcn_ds_swizzle(
          (int)__float_as_uint(h), 0x101F);  // BitMode xor-4: lane <-> lane^4
      f16x2 tp = __builtin_bit_cast(
          f16x2, __builtin_amdgcn_cvt_pkrtz(h, __uint_as_float(hsw)));
      unsigned tpu = __builtin_bit_cast(unsigned, tp);
      unsigned sp[8];
#pragma unroll
      for (int m = 0; m < 8; ++m) sp[m] = rdlane_u(tpu, 8 * m);

      float sx = rdlane(xr, s);  // x(g+1) — window pre-shifted by 1

      // ---- layer-1 pre-activation (step g+1): 8 dot2, 2 chains
      float accA = __fmaf_rn(wih1, sx, bb1);
      float accB = dot2f(wh1[1], sp[1], 0.f);
      accA = dot2f(wh1[0], sp[0], accA);
      accB = dot2f(wh1[3], sp[3], accB);
      accA = dot2f(wh1[2], sp[2], accA);
      accB = dot2f(wh1[5], sp[5], accB);
      accA = dot2f(wh1[4], sp[4], accA);
      accB = dot2f(wh1[7], sp[7], accB);
      accA = dot2f(wh1[6], sp[6], accA);
      float pre = accA + accB;

      // ---- layer-2 pre-activation (step g): same pairs, L2 weights
      float accC = __fmaf_rn(whh2, h2b, bb2);
      float accD = dot2f(wh2[1], sp[1], 0.f);
      accC = dot2f(wh2[0], sp[0], accC);
      accD = dot2f(wh2[3], sp[3], accD);
      accC = dot2f(wh2[2], sp[2], accC);
      accD = dot2f(wh2[5], sp[5], accD);
      accC = dot2f(wh2[4], sp[4], accC);
      accD = dot2f(wh2[7], sp[7], accD);
      accC = dot2f(wh2[6], sp[6], accC);
      float pre2 = accC + accD;

      // ---- layer-1 activation + state update -> h_new
      float a1 = __fmaf_rn(aA, rcpa(1.f + exp2a(pre)), aC);
      float i1 = qperm<QP_BC0>(a1);
      float f1 = qperm<QP_BC1>(a1);
      float g1 = qperm<QP_BC2>(a1);
      float o1 = qperm<QP_BC3>(a1);
      cs = __fmaf_rn(f1, cs, i1 * g1);
      float hn = o1 * __fmaf_rn(2.f, rcpa(1.f + exp2a(cs)), -1.f);

      // ---- layer-2 activation + state update -> ov (wave-uniform)
      float a2 = __fmaf_rn(aA, rcpa(1.f + exp2a(pre2)), aC);
      float i2 = qperm<QP_BC0>(a2);
      float f2 = qperm<QP_BC1>(a2);
      float g2 = qperm<QP_BC2>(a2);
      float o2 = qperm<QP_BC3>(a2);
      cs2 = __fmaf_rn(f2, cs2, i2 * g2);
      h2b = o2 * __fmaf_rn(2.f, rcpa(1.f + exp2a(cs2)), -1.f);
      float ov = h2b * m2;

      och = (lane == s) ? ov : och;
      h = hn;
    }

    ob[(ch << 6) + lane] = och;  // coalesced store
    xr = xnext;
  }
}

extern "C" void kernel_launch(void* const* d_in, const int* in_sizes, int n_in,
                              void* d_out, int out_size, void* d_ws, size_t ws_size,
                              hipStream_t stream) {
  const float* x     = (const float*)d_in[0];
  const float* Wih1  = (const float*)d_in[1];
  const float* Whh1  = (const float*)d_in[2];
  const float* b1    = (const float*)d_in[3];
  const float* Wih2  = (const float*)d_in[4];
  const float* Whh2  = (const float*)d_in[5];
  const float* b2    = (const float*)d_in[6];
  const float* mask1 = (const float*)d_in[7];
  const float* mask2 = (const float*)d_in[8];
  float* out = (float*)d_out;

  const int B = in_sizes[8];      // mask2 has B elements
  const int T = in_sizes[0] / B;  // x is [B,T,1]

  vdd_lstm_kernel<<<dim3(B), dim3(64), 0, stream>>>(
      x, Wih1, Whh1, b1, Wih2, Whh2, b2, mask1, mask2, out, T);
}

// Round 9
// 609.102 us; speedup vs baseline: 1.1018x; 1.0525x over previous
//
#include <hip/hip_runtime.h>

// ---------- types ----------
// NOTE: gfx builtins (cvt_pkrtz, fdot2) use __fp16 ext-vectors, NOT _Float16.
typedef __fp16 f16x2 __attribute__((ext_vector_type(2)));

// ---------- lane/scalar helpers ----------
static __device__ __forceinline__ float rdlane(float v, int l) {
  return __uint_as_float(__builtin_amdgcn_readlane(__float_as_uint(v), (unsigned)l));
}
static __device__ __forceinline__ unsigned rdlane_u(unsigned v, int l) {
  return __builtin_amdgcn_readlane(v, (unsigned)l);
}

template <int CTRL>
static __device__ __forceinline__ float qperm(float v) {
  // DPP quad_perm: explicit per-position select — direction-unambiguous.
  return __uint_as_float(__builtin_amdgcn_update_dpp(
      0u, __float_as_uint(v), CTRL, 0xF, 0xF, true));
}

// all lanes get (lo32-half value + hi32-half value) — verified R3-R8.
static __device__ __forceinline__ float xswapadd32(float v) {
  float a = v, b;
  asm("v_mov_b32 %0, %1\n\t"
      "s_nop 1\n\t"
      "v_permlane32_swap_b32 %1, %0"
      : "=&v"(b), "+v"(a));
  return a + b;
}

static __device__ __forceinline__ float exp2a(float x) {
  float r;
  asm("v_exp_f32 %0, %1" : "=v"(r) : "v"(x));
  return r;
}
static __device__ __forceinline__ float rcpa(float x) {
  return __builtin_amdgcn_rcpf(x);
}

// f32 += f16x2 . f16x2  (v_dot2_f32_f16: f16 multiply, f32 accumulate)
static __device__ __forceinline__ float dot2f(f16x2 a, unsigned bu, float c) {
#if __has_builtin(__builtin_amdgcn_fdot2)
  return __builtin_amdgcn_fdot2(a, __builtin_bit_cast(f16x2, bu), c, false);
#else
  float r = c;
  f16x2 b = __builtin_bit_cast(f16x2, bu);
  asm("v_dot2_f32_f16 %0, %1, %2, %0" : "+v"(r) : "v"(a), "v"(b));
  return r;
#endif
}

#define QP_BC0 0x00  // broadcast quad lane 0 (i)
#define QP_BC1 0x55  // broadcast quad lane 1 (f)
#define QP_BC2 0xAA  // broadcast quad lane 2 (g)
#define QP_BC3 0xFF  // broadcast quad lane 3 (o)

// lane = 4*j + gt (j: hidden unit 0..15, gt: gate i,f,g,o; torch row gt*16+j).
//
// Scale folding (R3): sigmoid rows *= -log2e, g rows *= -2log2e; g-gate
// output pre-scaled so cs = -2log2e*c; tanh(c) = 2*rcp(1+exp2(cs)) - 1.
// Pipeline (R4): body step g computes L2(g) and L1(g+1), both off h1(g).
// dot2 matvecs (R8): both layers share one f16 pair-broadcast, 8 SGPR pairs.
//
// NEW (R9): pair-building moved OFF the LDS pipe. Using the proven
// xswapadd32 (sum of 32-halves, direction-agnostic):
//   partner = xswapadd32(h) - h   == h[lane^32]  (1 ulp f32; absorbed by f16)
//   tp      = cvt_pkrtz(h, partner)  -> lane 4m holds {h[m], h[m+8]}
//   sp[m]   = readlane(tp, 4m), m=0..7   (source lanes all < 32)
// Weights are paired {k=m, k=m+8} to match.
__global__ __launch_bounds__(64, 1) void vdd_lstm_kernel(
    const float* __restrict__ x,      // [B,T]
    const float* __restrict__ Wih1,   // [64]
    const float* __restrict__ Whh1,   // [64,16]
    const float* __restrict__ b1,     // [64]
    const float* __restrict__ Wih2,   // [4,16]
    const float* __restrict__ Whh2,   // [4]
    const float* __restrict__ b2,     // [4]
    const float* __restrict__ mask1,  // [B,16]
    const float* __restrict__ mask2,  // [B]
    float* __restrict__ out,          // [B,T]
    int T) {
  const int b = blockIdx.x;
  const int lane = threadIdx.x;  // 64 threads
  const int j = lane >> 2;
  const int gt = lane & 3;
  const int row = gt * 16 + j;

  const float LOG2E = 1.4426950408889634f;
  const bool isg = (gt == 2);
  const float sc = isg ? (-2.f * LOG2E) : (-LOG2E);
  const float aA = isg ? (-4.f * LOG2E) : 1.f;
  const float aC = isg ? (2.f * LOG2E) : 0.f;

  // L1 weights as 8 f16 pairs {w[m], w[m+8]} (pre-scaled).
  f16x2 wh1[8];
#pragma unroll
  for (int m = 0; m < 8; ++m) {
    wh1[m].x = (__fp16)(Whh1[row * 16 + m] * sc);
    wh1[m].y = (__fp16)(Whh1[row * 16 + m + 8] * sc);
  }
  // L2 weights (mask1 + scale folded) as 8 f16 pairs {k=m, k=m+8}.
  f16x2 wh2[8];
#pragma unroll
  for (int m = 0; m < 8; ++m) {
    wh2[m].x = (__fp16)(Wih2[gt * 16 + m] * mask1[b * 16 + m] * sc);
    wh2[m].y = (__fp16)(Wih2[gt * 16 + m + 8] * mask1[b * 16 + m + 8] * sc);
  }
  const float wih1 = Wih1[row] * sc;
  const float bb1  = b1[row] * sc;
  const float whh2 = Whh2[gt] * sc;
  const float bb2  = b2[gt] * sc;
  const float m2   = mask2[b];

  const float* xb = x + (size_t)b * T;
  float* ob = out + (size_t)b * T;

  float h = 0.f, cs = 0.f;     // layer-1 state (all lanes)
  float cs2 = 0.f, h2b = 0.f;  // layer-2 state (all lanes)

  const int NCH = T >> 6;
  const int tmax = T - 1;

  // x window for chunk 0: x[1 + lane], clamped (coalesced).
  int idx0 = 1 + lane; idx0 = idx0 > tmax ? tmax : idx0;
  float xr = xb[idx0];

  // ---- prologue: layer-1 for step 0 (h_prev = 0) ----
  {
    float x0 = xb[0];  // uniform
    float pre = __fmaf_rn(wih1, x0, bb1);
    float a1 = __fmaf_rn(aA, rcpa(1.f + exp2a(pre)), aC);
    float i1 = qperm<QP_BC0>(a1);
    float g1 = qperm<QP_BC2>(a1);
    float o1 = qperm<QP_BC3>(a1);
    cs = i1 * g1;
    h = o1 * __fmaf_rn(2.f, rcpa(1.f + exp2a(cs)), -1.f);
  }

  for (int ch = 0; ch < NCH; ++ch) {
    // prefetch next chunk's shifted window (clamped; coalesced)
    int idxn = (ch + 1) * 64 + 1 + lane;
    idxn = idxn > tmax ? tmax : idxn;
    float xnext = xb[idxn];

    float och = 0.f;  // lane L accumulates out[ch*64 + L]

#pragma unroll 8
    for (int s = 0; s < 64; ++s) {
      // ---- f16 pair-broadcast of h = h1(g), pure VALU ----
      float hsum = xswapadd32(h);        // lo+hi halves, all lanes
      float partner = hsum - h;          // == h[lane^32] (up to 1 ulp)
      f16x2 tp = __builtin_bit_cast(
          f16x2, __builtin_amdgcn_cvt_pkrtz(h, partner));
      unsigned tpu = __builtin_bit_cast(unsigned, tp);
      unsigned sp[8];
#pragma unroll
      for (int m = 0; m < 8; ++m) sp[m] = rdlane_u(tpu, 4 * m);

      float sx = rdlane(xr, s);  // x(g+1) — window pre-shifted by 1

      // ---- layer-1 pre-activation (step g+1): 8 dot2, 2 chains
      float accA = __fmaf_rn(wih1, sx, bb1);
      float accB = dot2f(wh1[1], sp[1], 0.f);
      accA = dot2f(wh1[0], sp[0], accA);
      accB = dot2f(wh1[3], sp[3], accB);
      accA = dot2f(wh1[2], sp[2], accA);
      accB = dot2f(wh1[5], sp[5], accB);
      accA = dot2f(wh1[4], sp[4], accA);
      accB = dot2f(wh1[7], sp[7], accB);
      accA = dot2f(wh1[6], sp[6], accA);
      float pre = accA + accB;

      // ---- layer-2 pre-activation (step g): same pairs, L2 weights
      float accC = __fmaf_rn(whh2, h2b, bb2);
      float accD = dot2f(wh2[1], sp[1], 0.f);
      accC = dot2f(wh2[0], sp[0], accC);
      accD = dot2f(wh2[3], sp[3], accD);
      accC = dot2f(wh2[2], sp[2], accC);
      accD = dot2f(wh2[5], sp[5], accD);
      accC = dot2f(wh2[4], sp[4], accC);
      accD = dot2f(wh2[7], sp[7], accD);
      accC = dot2f(wh2[6], sp[6], accC);
      float pre2 = accC + accD;

      // ---- layer-1 activation + state update -> h_new
      float a1 = __fmaf_rn(aA, rcpa(1.f + exp2a(pre)), aC);
      float i1 = qperm<QP_BC0>(a1);
      float f1 = qperm<QP_BC1>(a1);
      float g1 = qperm<QP_BC2>(a1);
      float o1 = qperm<QP_BC3>(a1);
      cs = __fmaf_rn(f1, cs, i1 * g1);
      float hn = o1 * __fmaf_rn(2.f, rcpa(1.f + exp2a(cs)), -1.f);

      // ---- layer-2 activation + state update -> ov (wave-uniform)
      float a2 = __fmaf_rn(aA, rcpa(1.f + exp2a(pre2)), aC);
      float i2 = qperm<QP_BC0>(a2);
      float f2 = qperm<QP_BC1>(a2);
      float g2 = qperm<QP_BC2>(a2);
      float o2 = qperm<QP_BC3>(a2);
      cs2 = __fmaf_rn(f2, cs2, i2 * g2);
      h2b = o2 * __fmaf_rn(2.f, rcpa(1.f + exp2a(cs2)), -1.f);
      float ov = h2b * m2;

      och = (lane == s) ? ov : och;
      h = hn;
    }

    ob[(ch << 6) + lane] = och;  // coalesced store
    xr = xnext;
  }
}

extern "C" void kernel_launch(void* const* d_in, const int* in_sizes, int n_in,
                              void* d_out, int out_size, void* d_ws, size_t ws_size,
                              hipStream_t stream) {
  const float* x     = (const float*)d_in[0];
  const float* Wih1  = (const float*)d_in[1];
  const float* Whh1  = (const float*)d_in[2];
  const float* b1    = (const float*)d_in[3];
  const float* Wih2  = (const float*)d_in[4];
  const float* Whh2  = (const float*)d_in[5];
  const float* b2    = (const float*)d_in[6];
  const float* mask1 = (const float*)d_in[7];
  const float* mask2 = (const float*)d_in[8];
  float* out = (float*)d_out;

  const int B = in_sizes[8];      // mask2 has B elements
  const int T = in_sizes[0] / B;  // x is [B,T,1]

  vdd_lstm_kernel<<<dim3(B), dim3(64), 0, stream>>>(
      x, Wih1, Whh1, b1, Wih2, Whh2, b2, mask1, mask2, out, T);
}